// Round 17
// baseline (176.238 us; speedup 1.0000x reference)
//
#include <hip/hip_runtime.h>
#include <hip/hip_bf16.h>
#include <stdint.h>

using bf16 = __hip_bfloat16;
typedef __attribute__((ext_vector_type(8))) short short8;
typedef __attribute__((ext_vector_type(4))) float f32x4;
typedef __attribute__((ext_vector_type(4))) unsigned short u16x4;

__device__ __forceinline__ float bf2f(short u) {
  unsigned int b = ((unsigned int)(unsigned short)u) << 16;
  return __builtin_bit_cast(float, b);
}
__device__ __forceinline__ unsigned short f2bf(float f) {
  unsigned int u = __builtin_bit_cast(unsigned int, f);
  u += 0x7fffu + ((u >> 16) & 1u);  // RNE (finite values only)
  return (unsigned short)(u >> 16);
}

__device__ __forceinline__ void gload_lds16(const bf16* g, bf16* l) {
  __builtin_amdgcn_global_load_lds(
      (const __attribute__((address_space(1))) void*)g,
      (__attribute__((address_space(3))) void*)l, 16, 0, 0);
}

#define SCHED0 __builtin_amdgcn_sched_barrier(0)
#define BAR do { SCHED0; __builtin_amdgcn_s_barrier(); SCHED0; } while (0)
#define LGKM0 do { asm volatile("s_waitcnt lgkmcnt(0)" ::: "memory"); SCHED0; } while (0)
#define VMCNT6 asm volatile("s_waitcnt vmcnt(6)" ::: "memory")

// T1 XCD swizzle (m157/m204): hw-block i on XCD i%8; logical tile = (i%8)*q + i/8.
// Requires nwg % 8 == 0 (all our grids: 128/64/256/64-per-z/256).
#define XCD_SWZ(TILE)                                                          \
  int bx_ = blockIdx.x, by_ = blockIdx.y;                                      \
  {                                                                            \
    const int gx_ = gridDim.x;                                                 \
    const int nwg_ = gx_ * gridDim.y;                                          \
    int fl_ = by_ * gx_ + bx_;                                                 \
    fl_ = (fl_ & 7) * (nwg_ >> 3) + (fl_ >> 3);                                \
    bx_ = fl_ % gx_;                                                           \
    by_ = fl_ / gx_;                                                           \
  }                                                                            \
  const int m0 = by_ * (TILE);                                                 \
  const int n0 = bx_ * (TILE);

// ---------------- shared 6-phase helpers (R13-exact) ----------------
template <int BUF, int Q>
__device__ __forceinline__ void lds_A(const char* sm, int rbA, int sl0, int sl1,
                                      short8 (&aF)[4][2]) {
#pragma unroll
  for (int mi = 0; mi < 4; ++mi) {
    const char* p = sm + BUF * 65536 + rbA + (Q * 64 + mi * 16) * 128;
    aF[mi][0] = *(const short8*)(p + sl0);
    aF[mi][1] = *(const short8*)(p + sl1);
  }
}
template <int BUF, int H>
__device__ __forceinline__ void lds_B(const char* sm, int rbB, int sl0, int sl1,
                                      short8 (&bF)[2][2]) {
#pragma unroll
  for (int ni = 0; ni < 2; ++ni) {
    const char* p = sm + BUF * 65536 + rbB + (H * 32 + ni * 16) * 128;
    bF[ni][0] = *(const short8*)(p + sl0);
    bF[ni][1] = *(const short8*)(p + sl1);
  }
}
template <int Q, int H>
__device__ __forceinline__ void mfma_q(short8 (&aF)[4][2], short8 (&bF)[2][2],
                                       f32x4 (&acc)[8][4]) {
  __builtin_amdgcn_s_setprio(1);
#pragma unroll
  for (int mi = 0; mi < 4; ++mi)
#pragma unroll
    for (int ni = 0; ni < 2; ++ni)
#pragma unroll
      for (int kk = 0; kk < 2; ++kk)
        acc[Q * 4 + mi][H * 2 + ni] = __builtin_amdgcn_mfma_f32_16x16x32_bf16(
            aF[mi][kk], bF[ni][kk], acc[Q * 4 + mi][H * 2 + ni], 0, 0, 0);
  __builtin_amdgcn_s_setprio(0);
}

// the 6-phase main loop, shared verbatim by both kernels (R6 sync structure + T1 swizzle)
#define GEMM256_PREAMBLE_AND_LOOP                                              \
  __shared__ __align__(16) char sm[131072];                                    \
  const int kz = blockIdx.z * K;                                               \
  A += kz;                                                                     \
  Bt += kz;                                                                    \
  const int tid = threadIdx.x;                                                 \
  const int wid = tid >> 6;                                                    \
  const int lane = tid & 63;                                                   \
  XCD_SWZ(256)                                                                 \
  const int NT = K >> 6;                                                       \
  const int NI = NT >> 1;                                                      \
  const int sr = tid >> 3;                                                     \
  const int scs = ((tid & 7) ^ (sr & 7)) << 3;                                 \
  const bf16* Ag = A + (size_t)(m0 + sr) * lda + scs;                          \
  const bf16* Bg = Bt + (size_t)(n0 + sr) * ldb + scs;                         \
  const int stW = wid * 8 * 128;                                               \
  const int lr = lane & 15;                                                    \
  const int rbA = ((wid >> 2) * 128 + lr) * 128;                               \
  const int rbB = 32768 + ((wid & 3) * 64 + lr) * 128;                         \
  const int sl0 = (((lane >> 4) ^ (lane & 7)) << 4);                           \
  const int sl1 = ((((lane >> 4) + 4) ^ (lane & 7)) << 4);                     \
  f32x4 acc[8][4] = {};                                                        \
  short8 aF[4][2], b0F[2][2], b1F[2][2];                                       \
  auto stageA = [&](int buf, int tile, int half) {                             \
    const bf16* s = Ag + (size_t)(half * 128) * lda + tile * 64;               \
    char* d = sm + buf * 65536 + (half * 128) * 128 + stW;                     \
    gload_lds16(s, (bf16*)d);                                                  \
    gload_lds16(s + (size_t)64 * lda, (bf16*)(d + 64 * 128));                  \
  };                                                                           \
  auto stageB = [&](int buf, int tile, int half) {                             \
    const bf16* s = Bg + (size_t)(half * 128) * ldb + tile * 64;               \
    char* d = sm + buf * 65536 + 32768 + (half * 128) * 128 + stW;             \
    gload_lds16(s, (bf16*)d);                                                  \
    gload_lds16(s + (size_t)64 * ldb, (bf16*)(d + 64 * 128));                  \
  };                                                                           \
  stageA(0, 0, 0); stageA(0, 0, 1); stageB(0, 0, 0); stageB(0, 0, 1);          \
  stageB(1, 1, 0); stageB(1, 1, 1); stageA(1, 1, 0);                           \
  VMCNT6;                                                                      \
  BAR;                                                                         \
  for (int i = 0; i < NI; ++i) {                                               \
    const int t1 = 2 * i + 1;                                                  \
    const int t2 = (2 * i + 2 < NT) ? 2 * i + 2 : NT - 1;                      \
    const int t3 = (2 * i + 3 < NT) ? 2 * i + 3 : NT - 1;                      \
    lds_A<0, 0>(sm, rbA, sl0, sl1, aF);                                        \
    lds_B<0, 0>(sm, rbB, sl0, sl1, b0F);                                       \
    lds_B<0, 1>(sm, rbB, sl0, sl1, b1F);                                       \
    stageA(1, t1, 1);                                                          \
    BAR; LGKM0;                                                                \
    mfma_q<0, 0>(aF, b0F, acc);                                                \
    mfma_q<0, 1>(aF, b1F, acc);                                                \
    BAR;                                                                       \
    lds_A<0, 1>(sm, rbA, sl0, sl1, aF);                                        \
    stageB(0, t2, 0);                                                          \
    BAR; LGKM0; mfma_q<1, 1>(aF, b1F, acc); BAR;                               \
    stageB(0, t2, 1); stageA(0, t2, 0);                                        \
    VMCNT6;                                                                    \
    BAR; mfma_q<1, 0>(aF, b0F, acc); BAR;                                      \
    lds_A<1, 0>(sm, rbA, sl0, sl1, aF);                                        \
    lds_B<1, 0>(sm, rbB, sl0, sl1, b0F);                                       \
    lds_B<1, 1>(sm, rbB, sl0, sl1, b1F);                                       \
    stageA(0, t2, 1);                                                          \
    BAR; LGKM0;                                                                \
    mfma_q<0, 0>(aF, b0F, acc);                                                \
    mfma_q<0, 1>(aF, b1F, acc);                                                \
    BAR;                                                                       \
    lds_A<1, 1>(sm, rbA, sl0, sl1, aF);                                        \
    stageB(1, t3, 0);                                                          \
    BAR; LGKM0; mfma_q<1, 1>(aF, b1F, acc); BAR;                               \
    stageB(1, t3, 1); stageA(1, t3, 0);                                        \
    VMCNT6;                                                                    \
    BAR; mfma_q<1, 0>(aF, b0F, acc); BAR;                                      \
  }                                                                            \
  const int cr = (lane >> 4) * 4;                                              \
  const int cc = lane & 15;                                                    \
  const int wm = (wid >> 2) * 128;                                             \
  const int wn = (wid & 3) * 64;

// ---------------- plain 256x256 6-phase GEMM ----------------
template <typename OutT, int TAG>
__global__ __launch_bounds__(512, 2)
void gemm256(const bf16* __restrict__ A, int lda,
             const bf16* __restrict__ Bt, int ldb,
             OutT* __restrict__ C, int ldc, int K, size_t splitStride) {
  C += (size_t)blockIdx.z * splitStride;
  GEMM256_PREAMBLE_AND_LOOP
#pragma unroll
  for (int mi = 0; mi < 8; ++mi)
#pragma unroll
    for (int ni = 0; ni < 4; ++ni) {
      const int row = m0 + wm + mi * 16 + cr;
      const int col = n0 + wn + ni * 16 + cc;
#pragma unroll
      for (int j = 0; j < 4; ++j) {
        float v = acc[mi][ni][j];
        if constexpr (sizeof(OutT) == 2)
          ((unsigned short*)C)[(size_t)(row + j) * ldc + col] = f2bf(v);
        else
          C[(size_t)(row + j) * ldc + col] = v;
      }
    }
}

// ---------------- QK^T clone: P = exp(acc) fused into store loop + Zp partials ----------------
__global__ __launch_bounds__(512, 2)
void gemm256x(const bf16* __restrict__ A, int lda,
              const bf16* __restrict__ Bt, int ldb,
              bf16* __restrict__ C, int ldc, int K,
              float* __restrict__ Zp) {
  GEMM256_PREAMBLE_AND_LOOP
  const int wc = wid & 3;
#pragma unroll
  for (int mi = 0; mi < 8; ++mi) {
    const int row = m0 + wm + mi * 16 + cr;
    float rs0 = 0.f, rs1 = 0.f, rs2 = 0.f, rs3 = 0.f;
#pragma unroll
    for (int ni = 0; ni < 4; ++ni) {
      const int col = n0 + wn + ni * 16 + cc;
      float e0 = __expf(acc[mi][ni][0]);
      float e1 = __expf(acc[mi][ni][1]);
      float e2 = __expf(acc[mi][ni][2]);
      float e3 = __expf(acc[mi][ni][3]);
      ((unsigned short*)C)[(size_t)(row + 0) * ldc + col] = f2bf(e0);
      ((unsigned short*)C)[(size_t)(row + 1) * ldc + col] = f2bf(e1);
      ((unsigned short*)C)[(size_t)(row + 2) * ldc + col] = f2bf(e2);
      ((unsigned short*)C)[(size_t)(row + 3) * ldc + col] = f2bf(e3);
      rs0 += e0; rs1 += e1; rs2 += e2; rs3 += e3;
    }
#pragma unroll
    for (int off = 1; off < 16; off <<= 1) {
      rs0 += __shfl_xor(rs0, off);
      rs1 += __shfl_xor(rs1, off);
      rs2 += __shfl_xor(rs2, off);
      rs3 += __shfl_xor(rs3, off);
    }
    if ((lane & 15) == 0) {
      f32x4 rsv;
      rsv[0] = rs0; rsv[1] = rs1; rsv[2] = rs2; rsv[3] = rs3;
      *(f32x4*)&Zp[(size_t)(bx_ * 4 + wc) * 4096 + row] = rsv;
    }
  }
}

// ---------------- m97-structure 128x128 GEMM (out-proj) ----------------
template <typename OutT, int TAG>
__global__ __launch_bounds__(256)
void gemm_bt(const bf16* __restrict__ A, int lda,
             const bf16* __restrict__ Bt, int ldb,
             OutT* __restrict__ C, int ldc, int K, size_t splitStride) {
  constexpr int BK = 64;
  __shared__ __align__(16) bf16 As[128 * BK];
  __shared__ __align__(16) bf16 Bs[128 * BK];

  const int kz = blockIdx.z * K;
  A += kz;
  Bt += kz;
  C += (size_t)blockIdx.z * splitStride;

  const int tid = threadIdx.x;
  const int wid = tid >> 6;
  const int lane = tid & 63;
  XCD_SWZ(128)

  const int arow = tid >> 3;
  const int acol = (tid & 7) * 8;
  const int lr = lane & 15;
  const int lk = (lane >> 4) * 8;
  const int wm = (wid >> 1) * 64;
  const int wn = (wid & 1) * 64;

  const bf16* Ag = A + (size_t)(m0 + arow) * lda + acol;
  const bf16* Bg = Bt + (size_t)(n0 + arow) * ldb + acol;
  bf16* Asw = As + wid * 512;
  bf16* Bsw = Bs + wid * 512;

  f32x4 acc[4][4] = {};

  for (int kt = 0; kt < K; kt += BK) {
    __syncthreads();
#pragma unroll
    for (int r = 0; r < 4; ++r) {
      gload_lds16(Ag + (size_t)(r * 32) * lda + kt, Asw + r * 2048);
      gload_lds16(Bg + (size_t)(r * 32) * ldb + kt, Bsw + r * 2048);
    }
    __syncthreads();
#pragma unroll
    for (int kk = 0; kk < BK; kk += 32) {
      short8 a[4], b[4];
#pragma unroll
      for (int i = 0; i < 4; ++i)
        a[i] = *(const short8*)&As[(wm + i * 16 + lr) * BK + kk + lk];
#pragma unroll
      for (int i = 0; i < 4; ++i)
        b[i] = *(const short8*)&Bs[(wn + i * 16 + lr) * BK + kk + lk];
#pragma unroll
      for (int mi = 0; mi < 4; ++mi)
#pragma unroll
        for (int ni = 0; ni < 4; ++ni)
          acc[mi][ni] = __builtin_amdgcn_mfma_f32_16x16x32_bf16(
              a[mi], b[ni], acc[mi][ni], 0, 0, 0);
    }
  }

  const int cr = (lane >> 4) * 4;
  const int cc = lane & 15;
#pragma unroll
  for (int mi = 0; mi < 4; ++mi)
#pragma unroll
    for (int ni = 0; ni < 4; ++ni) {
      const int row = m0 + wm + mi * 16 + cr;
      const int col = n0 + wn + ni * 16 + cc;
#pragma unroll
      for (int j = 0; j < 4; ++j) {
        float v = acc[mi][ni][j];
        if constexpr (sizeof(OutT) == 2)
          ((unsigned short*)C)[(size_t)(row + j) * ldc + col] = f2bf(v);
        else
          C[(size_t)(row + j) * ldc + col] = v;
      }
    }
}

// yb[i] = bf16( (sum_{z<4} p[z*stride+i]) / Z[row] ),  Z[row] = sum_{b<64} Zp[b][row].
__global__ __launch_bounds__(256)
void reduce4_norm(const unsigned short* __restrict__ p, const float* __restrict__ Zp,
                  unsigned short* __restrict__ yb, int n) {
  __shared__ float sZ[2];
  const int tid = threadIdx.x;
  const int row0 = blockIdx.x * 2;
  if (tid < 128) {
    const int w = tid >> 6;        // 0 or 1 -> row0 or row0+1
    const int b = tid & 63;        // partial index
    float zv = Zp[(size_t)b * 4096 + row0 + w];
#pragma unroll
    for (int off = 1; off < 64; off <<= 1) zv += __shfl_xor(zv, off);
    if (b == 0) sZ[w] = zv;
  }
  __syncthreads();
  const float inv = 1.f / sZ[tid >> 7];
  const int i = blockIdx.x * 2048 + tid * 8;
  const size_t st = (size_t)n;
  short8 a = *(const short8*)&p[i];
  short8 b = *(const short8*)&p[i + st];
  short8 c = *(const short8*)&p[i + 2 * st];
  short8 d = *(const short8*)&p[i + 3 * st];
  short8 o;
#pragma unroll
  for (int j = 0; j < 8; ++j)
    o[j] = (short)f2bf((bf2f(a[j]) + bf2f(b[j]) + bf2f(c[j]) + bf2f(d[j])) * inv);
  *(short8*)&yb[i] = o;
}

// Fused 4x weight transpose: z in {0:Wk,1:Wq(x0.06),2:Wv} -> Wt + z*1M; 3:Wo -> Wot.
__global__ __launch_bounds__(256)
void tr4_f32_bf16(const float* __restrict__ s0, const float* __restrict__ s1,
                  const float* __restrict__ s2, const float* __restrict__ s3,
                  unsigned short* __restrict__ dWt, unsigned short* __restrict__ dWot) {
  __shared__ float t[32][33];
  const int z = blockIdx.z;
  const float* src = (z == 0) ? s0 : (z == 1) ? s1 : (z == 2) ? s2 : s3;
  unsigned short* dst = (z == 3) ? dWot : dWt + (size_t)z * 1024 * 1024;
  const float scale = (z == 1) ? 0.06f : 1.0f;
  const int bx = blockIdx.x * 32;
  const int by = blockIdx.y * 32;
  const int tx = threadIdx.x, ty = threadIdx.y;
#pragma unroll
  for (int j = 0; j < 4; ++j)
    t[ty + j * 8][tx] = src[(size_t)(by + ty + j * 8) * 1024 + bx + tx];
  __syncthreads();
#pragma unroll
  for (int j = 0; j < 4; ++j)
    dst[(size_t)(bx + ty + j * 8) * 1024 + by + tx] = f2bf(t[tx][ty + j * 8] * scale);
}

__global__ __launch_bounds__(256)
void cvt_f32_bf16(const float* __restrict__ src, unsigned short* __restrict__ dst, int n) {
  const int i = (blockIdx.x * 256 + threadIdx.x) * 4;
  if (i >= n) return;
  f32x4 v = *(const f32x4*)&src[i];
  u16x4 o;
#pragma unroll
  for (int j = 0; j < 4; ++j) o[j] = f2bf(v[j]);
  *(u16x4*)&dst[i] = o;
}

extern "C" void kernel_launch(void* const* d_in, const int* in_sizes, int n_in,
                              void* d_out, int out_size, void* d_ws, size_t ws_size,
                              hipStream_t stream) {
  const float* x = (const float*)d_in[0];
  const float* Wk = (const float*)d_in[1];
  const float* Wq = (const float*)d_in[2];
  const float* Wv = (const float*)d_in[3];
  const float* Wo = (const float*)d_in[4];
  float* out = (float*)d_out;

  // workspace layout (bf16 elements); total 74 MB (<= 80 MB proven available).
  // OVERLAY AUDIT (R16 bug fix): p4 = [0,32) MB — everything in that window must be
  // dead at att@V time: xb [0,8) dead after Vt-GEMM; Wt [8,14) dead after Vt-GEMM;
  // KQ [14,30) dead after gemm256x; [30,32) explicit PAD (never live).
  // Wot moved to [72,74) — beyond S's exclusive end (72), read only by outproj.
  bf16* xb  = (bf16*)d_ws;                          // [0,8)
  bf16* Wt  = xb + (size_t)4096 * 1024;             // [8,14)  Wk^T|.06Wq^T|Wv^T
  bf16* KQ  = Wt + (size_t)3072 * 1024;             // [14,30) K|Q
  // [30,32) pad
  bf16* Vt  = (bf16*)d_ws + (size_t)16 * 1024 * 1024;  // [32,40) V^T (GEMM-direct)
  bf16* S   = Vt + (size_t)1024 * 4096;             // [40,72) P = exp(QK^T)
  bf16* Wot = S + (size_t)4096 * 4096;              // [72,74) Wo^T
  bf16* p4  = xb;  // 4 x [4096][1024] att@V partials over dead xb/Wt/KQ/pad  [0,32)
  bf16* yb  = S;   // [4096][1024] y over dead S                              [40,48)
  // Zp [64][4096] f32 = 1 MB stashed in d_out (dead until outproj writes it)
  float* Zp = out;

  const dim3 tb(32, 8);

  cvt_f32_bf16<<<dim3(4096), dim3(256), 0, stream>>>(x, (unsigned short*)xb, 4096 * 1024);
  tr4_f32_bf16<<<dim3(32, 32, 4), tb, 0, stream>>>(
      Wk, Wq, Wv, Wo, (unsigned short*)Wt, (unsigned short*)Wot);

  // KQ = xb @ [Wk^T|Wq^T]^T   [4096 x 2048], K=1024   (128 blocks, 6-phase 256², T1)
  gemm256<bf16, 0><<<dim3(8, 16, 1), dim3(512), 0, stream>>>(
      xb, 1024, Wt, 1024, KQ, 2048, 1024, 0);

  // Vt = Wv^T @ x^T directly: C[d][n] = sum_k WvT[d][k]*xb[n][k]   [1024 x 4096]
  // (same gemm256<bf16,0> instantiation — swapped operand roles replace tr_bf16)
  gemm256<bf16, 0><<<dim3(16, 4, 1), dim3(512), 0, stream>>>(
      Wt + (size_t)2048 * 1024, 1024, xb, 1024, Vt, 4096, 1024, 0);

  // P = exp(Q @ K^T), Zp[64][4096] per-wave row-sum partials (256 blocks, T1 swizzle)
  gemm256x<<<dim3(16, 16, 1), dim3(512), 0, stream>>>(
      KQ + 1024, 2048, KQ, 2048, S, 4096, 1024, Zp);

  // p4[z] = P @ V, split-K=4 (64 blocks per z, 6-phase 256², T1 swizzle per z-slice)
  gemm256<bf16, 2><<<dim3(4, 16, 4), dim3(512), 0, stream>>>(
      S, 4096, Vt, 4096, p4, 1024, 1024, (size_t)4096 * 1024);

  // yb = (sum of 4 partials) / Z  (softmax normalization folded in)
  reduce4_norm<<<dim3(2048), dim3(256), 0, stream>>>(
      (const unsigned short*)p4, Zp, (unsigned short*)yb, 4096 * 1024);

  // out = yb @ Wot^T   [4096 x 1024], K=1024, fp32 out (m97 kernel, T1 swizzle)
  gemm_bt<float, 3><<<dim3(8, 32, 1), dim3(256), 0, stream>>>(
      yb, 1024, Wot, 1024, out, 1024, 1024, 0);
}

// Round 18
// 153.628 us; speedup vs baseline: 1.1472x; 1.1472x over previous
//
#include <hip/hip_runtime.h>
#include <hip/hip_bf16.h>
#include <stdint.h>

using bf16 = __hip_bfloat16;
typedef __attribute__((ext_vector_type(8))) short short8;
typedef __attribute__((ext_vector_type(4))) float f32x4;
typedef __attribute__((ext_vector_type(4))) unsigned short u16x4;

__device__ __forceinline__ float bf2f(short u) {
  unsigned int b = ((unsigned int)(unsigned short)u) << 16;
  return __builtin_bit_cast(float, b);
}
__device__ __forceinline__ unsigned short f2bf(float f) {
  unsigned int u = __builtin_bit_cast(unsigned int, f);
  u += 0x7fffu + ((u >> 16) & 1u);  // RNE (finite values only)
  return (unsigned short)(u >> 16);
}

__device__ __forceinline__ void gload_lds16(const bf16* g, bf16* l) {
  __builtin_amdgcn_global_load_lds(
      (const __attribute__((address_space(1))) void*)g,
      (__attribute__((address_space(3))) void*)l, 16, 0, 0);
}

#define SCHED0 __builtin_amdgcn_sched_barrier(0)
#define BAR do { SCHED0; __builtin_amdgcn_s_barrier(); SCHED0; } while (0)
#define LGKM0 do { asm volatile("s_waitcnt lgkmcnt(0)" ::: "memory"); SCHED0; } while (0)
#define VMCNT6 asm volatile("s_waitcnt vmcnt(6)" ::: "memory")

// T1 XCD swizzle (m157/m204): hw-block i on XCD i%8; logical tile = (i%8)*q + i/8.
// Requires nwg % 8 == 0 (all our grids: 256/192/64-per-z/256).
#define XCD_SWZ(TILE)                                                          \
  int bx_ = blockIdx.x, by_ = blockIdx.y;                                      \
  {                                                                            \
    const int gx_ = gridDim.x;                                                 \
    const int nwg_ = gx_ * gridDim.y;                                          \
    int fl_ = by_ * gx_ + bx_;                                                 \
    fl_ = (fl_ & 7) * (nwg_ >> 3) + (fl_ >> 3);                                \
    bx_ = fl_ % gx_;                                                           \
    by_ = fl_ / gx_;                                                           \
  }                                                                            \
  const int m0 = by_ * (TILE);                                                 \
  const int n0 = bx_ * (TILE);

// ---------------- shared 6-phase helpers (R13-exact) ----------------
template <int BUF, int Q>
__device__ __forceinline__ void lds_A(const char* sm, int rbA, int sl0, int sl1,
                                      short8 (&aF)[4][2]) {
#pragma unroll
  for (int mi = 0; mi < 4; ++mi) {
    const char* p = sm + BUF * 65536 + rbA + (Q * 64 + mi * 16) * 128;
    aF[mi][0] = *(const short8*)(p + sl0);
    aF[mi][1] = *(const short8*)(p + sl1);
  }
}
template <int BUF, int H>
__device__ __forceinline__ void lds_B(const char* sm, int rbB, int sl0, int sl1,
                                      short8 (&bF)[2][2]) {
#pragma unroll
  for (int ni = 0; ni < 2; ++ni) {
    const char* p = sm + BUF * 65536 + rbB + (H * 32 + ni * 16) * 128;
    bF[ni][0] = *(const short8*)(p + sl0);
    bF[ni][1] = *(const short8*)(p + sl1);
  }
}
template <int Q, int H>
__device__ __forceinline__ void mfma_q(short8 (&aF)[4][2], short8 (&bF)[2][2],
                                       f32x4 (&acc)[8][4]) {
  __builtin_amdgcn_s_setprio(1);
#pragma unroll
  for (int mi = 0; mi < 4; ++mi)
#pragma unroll
    for (int ni = 0; ni < 2; ++ni)
#pragma unroll
      for (int kk = 0; kk < 2; ++kk)
        acc[Q * 4 + mi][H * 2 + ni] = __builtin_amdgcn_mfma_f32_16x16x32_bf16(
            aF[mi][kk], bF[ni][kk], acc[Q * 4 + mi][H * 2 + ni], 0, 0, 0);
  __builtin_amdgcn_s_setprio(0);
}

// the 6-phase main loop, shared verbatim by both kernels (R6 sync structure + T1 swizzle)
#define GEMM256_PREAMBLE_AND_LOOP                                              \
  __shared__ __align__(16) char sm[131072];                                    \
  const int kz = blockIdx.z * K;                                               \
  A += kz;                                                                     \
  Bt += kz;                                                                    \
  const int tid = threadIdx.x;                                                 \
  const int wid = tid >> 6;                                                    \
  const int lane = tid & 63;                                                   \
  XCD_SWZ(256)                                                                 \
  const int NT = K >> 6;                                                       \
  const int NI = NT >> 1;                                                      \
  const int sr = tid >> 3;                                                     \
  const int scs = ((tid & 7) ^ (sr & 7)) << 3;                                 \
  const bf16* Ag = A + (size_t)(m0 + sr) * lda + scs;                          \
  const bf16* Bg = Bt + (size_t)(n0 + sr) * ldb + scs;                         \
  const int stW = wid * 8 * 128;                                               \
  const int lr = lane & 15;                                                    \
  const int rbA = ((wid >> 2) * 128 + lr) * 128;                               \
  const int rbB = 32768 + ((wid & 3) * 64 + lr) * 128;                         \
  const int sl0 = (((lane >> 4) ^ (lane & 7)) << 4);                           \
  const int sl1 = ((((lane >> 4) + 4) ^ (lane & 7)) << 4);                     \
  f32x4 acc[8][4] = {};                                                        \
  short8 aF[4][2], b0F[2][2], b1F[2][2];                                       \
  auto stageA = [&](int buf, int tile, int half) {                             \
    const bf16* s = Ag + (size_t)(half * 128) * lda + tile * 64;               \
    char* d = sm + buf * 65536 + (half * 128) * 128 + stW;                     \
    gload_lds16(s, (bf16*)d);                                                  \
    gload_lds16(s + (size_t)64 * lda, (bf16*)(d + 64 * 128));                  \
  };                                                                           \
  auto stageB = [&](int buf, int tile, int half) {                             \
    const bf16* s = Bg + (size_t)(half * 128) * ldb + tile * 64;               \
    char* d = sm + buf * 65536 + 32768 + (half * 128) * 128 + stW;             \
    gload_lds16(s, (bf16*)d);                                                  \
    gload_lds16(s + (size_t)64 * ldb, (bf16*)(d + 64 * 128));                  \
  };                                                                           \
  stageA(0, 0, 0); stageA(0, 0, 1); stageB(0, 0, 0); stageB(0, 0, 1);          \
  stageB(1, 1, 0); stageB(1, 1, 1); stageA(1, 1, 0);                           \
  VMCNT6;                                                                      \
  BAR;                                                                         \
  for (int i = 0; i < NI; ++i) {                                               \
    const int t1 = 2 * i + 1;                                                  \
    const int t2 = (2 * i + 2 < NT) ? 2 * i + 2 : NT - 1;                      \
    const int t3 = (2 * i + 3 < NT) ? 2 * i + 3 : NT - 1;                      \
    lds_A<0, 0>(sm, rbA, sl0, sl1, aF);                                        \
    lds_B<0, 0>(sm, rbB, sl0, sl1, b0F);                                       \
    lds_B<0, 1>(sm, rbB, sl0, sl1, b1F);                                       \
    stageA(1, t1, 1);                                                          \
    BAR; LGKM0;                                                                \
    mfma_q<0, 0>(aF, b0F, acc);                                                \
    mfma_q<0, 1>(aF, b1F, acc);                                                \
    BAR;                                                                       \
    lds_A<0, 1>(sm, rbA, sl0, sl1, aF);                                        \
    stageB(0, t2, 0);                                                          \
    BAR; LGKM0; mfma_q<1, 1>(aF, b1F, acc); BAR;                               \
    stageB(0, t2, 1); stageA(0, t2, 0);                                        \
    VMCNT6;                                                                    \
    BAR; mfma_q<1, 0>(aF, b0F, acc); BAR;                                      \
    lds_A<1, 0>(sm, rbA, sl0, sl1, aF);                                        \
    lds_B<1, 0>(sm, rbB, sl0, sl1, b0F);                                       \
    lds_B<1, 1>(sm, rbB, sl0, sl1, b1F);                                       \
    stageA(0, t2, 1);                                                          \
    BAR; LGKM0;                                                                \
    mfma_q<0, 0>(aF, b0F, acc);                                                \
    mfma_q<0, 1>(aF, b1F, acc);                                                \
    BAR;                                                                       \
    lds_A<1, 1>(sm, rbA, sl0, sl1, aF);                                        \
    stageB(1, t3, 0);                                                          \
    BAR; LGKM0; mfma_q<1, 1>(aF, b1F, acc); BAR;                               \
    stageB(1, t3, 1); stageA(1, t3, 0);                                        \
    VMCNT6;                                                                    \
    BAR; mfma_q<1, 0>(aF, b0F, acc); BAR;                                      \
  }                                                                            \
  const int cr = (lane >> 4) * 4;                                              \
  const int cc = lane & 15;                                                    \
  const int wm = (wid >> 2) * 128;                                             \
  const int wn = (wid & 3) * 64;

// ---------------- plain 256x256 6-phase GEMM ----------------
template <typename OutT, int TAG>
__global__ __launch_bounds__(512, 2)
void gemm256(const bf16* __restrict__ A, int lda,
             const bf16* __restrict__ Bt, int ldb,
             OutT* __restrict__ C, int ldc, int K, size_t splitStride) {
  C += (size_t)blockIdx.z * splitStride;
  GEMM256_PREAMBLE_AND_LOOP
#pragma unroll
  for (int mi = 0; mi < 8; ++mi)
#pragma unroll
    for (int ni = 0; ni < 4; ++ni) {
      const int row = m0 + wm + mi * 16 + cr;
      const int col = n0 + wn + ni * 16 + cc;
#pragma unroll
      for (int j = 0; j < 4; ++j) {
        float v = acc[mi][ni][j];
        if constexpr (sizeof(OutT) == 2)
          ((unsigned short*)C)[(size_t)(row + j) * ldc + col] = f2bf(v);
        else
          C[(size_t)(row + j) * ldc + col] = v;
      }
    }
}

// ---------------- QK^T clone: P = exp(acc) fused into store loop + Zp partials ----------------
__global__ __launch_bounds__(512, 2)
void gemm256x(const bf16* __restrict__ A, int lda,
              const bf16* __restrict__ Bt, int ldb,
              bf16* __restrict__ C, int ldc, int K,
              float* __restrict__ Zp) {
  GEMM256_PREAMBLE_AND_LOOP
  const int wc = wid & 3;
#pragma unroll
  for (int mi = 0; mi < 8; ++mi) {
    const int row = m0 + wm + mi * 16 + cr;
    float rs0 = 0.f, rs1 = 0.f, rs2 = 0.f, rs3 = 0.f;
#pragma unroll
    for (int ni = 0; ni < 4; ++ni) {
      const int col = n0 + wn + ni * 16 + cc;
      float e0 = __expf(acc[mi][ni][0]);
      float e1 = __expf(acc[mi][ni][1]);
      float e2 = __expf(acc[mi][ni][2]);
      float e3 = __expf(acc[mi][ni][3]);
      ((unsigned short*)C)[(size_t)(row + 0) * ldc + col] = f2bf(e0);
      ((unsigned short*)C)[(size_t)(row + 1) * ldc + col] = f2bf(e1);
      ((unsigned short*)C)[(size_t)(row + 2) * ldc + col] = f2bf(e2);
      ((unsigned short*)C)[(size_t)(row + 3) * ldc + col] = f2bf(e3);
      rs0 += e0; rs1 += e1; rs2 += e2; rs3 += e3;
    }
#pragma unroll
    for (int off = 1; off < 16; off <<= 1) {
      rs0 += __shfl_xor(rs0, off);
      rs1 += __shfl_xor(rs1, off);
      rs2 += __shfl_xor(rs2, off);
      rs3 += __shfl_xor(rs3, off);
    }
    if ((lane & 15) == 0) {
      f32x4 rsv;
      rsv[0] = rs0; rsv[1] = rs1; rsv[2] = rs2; rsv[3] = rs3;
      *(f32x4*)&Zp[(size_t)(bx_ * 4 + wc) * 4096 + row] = rsv;
    }
  }
}

// ---------------- m97-structure 128x128 GEMM (out-proj) ----------------
template <typename OutT, int TAG>
__global__ __launch_bounds__(256)
void gemm_bt(const bf16* __restrict__ A, int lda,
             const bf16* __restrict__ Bt, int ldb,
             OutT* __restrict__ C, int ldc, int K, size_t splitStride) {
  constexpr int BK = 64;
  __shared__ __align__(16) bf16 As[128 * BK];
  __shared__ __align__(16) bf16 Bs[128 * BK];

  const int kz = blockIdx.z * K;
  A += kz;
  Bt += kz;
  C += (size_t)blockIdx.z * splitStride;

  const int tid = threadIdx.x;
  const int wid = tid >> 6;
  const int lane = tid & 63;
  XCD_SWZ(128)

  const int arow = tid >> 3;
  const int acol = (tid & 7) * 8;
  const int lr = lane & 15;
  const int lk = (lane >> 4) * 8;
  const int wm = (wid >> 1) * 64;
  const int wn = (wid & 1) * 64;

  const bf16* Ag = A + (size_t)(m0 + arow) * lda + acol;
  const bf16* Bg = Bt + (size_t)(n0 + arow) * ldb + acol;
  bf16* Asw = As + wid * 512;
  bf16* Bsw = Bs + wid * 512;

  f32x4 acc[4][4] = {};

  for (int kt = 0; kt < K; kt += BK) {
    __syncthreads();
#pragma unroll
    for (int r = 0; r < 4; ++r) {
      gload_lds16(Ag + (size_t)(r * 32) * lda + kt, Asw + r * 2048);
      gload_lds16(Bg + (size_t)(r * 32) * ldb + kt, Bsw + r * 2048);
    }
    __syncthreads();
#pragma unroll
    for (int kk = 0; kk < BK; kk += 32) {
      short8 a[4], b[4];
#pragma unroll
      for (int i = 0; i < 4; ++i)
        a[i] = *(const short8*)&As[(wm + i * 16 + lr) * BK + kk + lk];
#pragma unroll
      for (int i = 0; i < 4; ++i)
        b[i] = *(const short8*)&Bs[(wn + i * 16 + lr) * BK + kk + lk];
#pragma unroll
      for (int mi = 0; mi < 4; ++mi)
#pragma unroll
        for (int ni = 0; ni < 4; ++ni)
          acc[mi][ni] = __builtin_amdgcn_mfma_f32_16x16x32_bf16(
              a[mi], b[ni], acc[mi][ni], 0, 0, 0);
    }
  }

  const int cr = (lane >> 4) * 4;
  const int cc = lane & 15;
#pragma unroll
  for (int mi = 0; mi < 4; ++mi)
#pragma unroll
    for (int ni = 0; ni < 4; ++ni) {
      const int row = m0 + wm + mi * 16 + cr;
      const int col = n0 + wn + ni * 16 + cc;
#pragma unroll
      for (int j = 0; j < 4; ++j) {
        float v = acc[mi][ni][j];
        if constexpr (sizeof(OutT) == 2)
          ((unsigned short*)C)[(size_t)(row + j) * ldc + col] = f2bf(v);
        else
          C[(size_t)(row + j) * ldc + col] = v;
      }
    }
}

// yb[i] = bf16( (sum_{z<4} p[z*stride+i]) / Z[row] ),  Z[row] = sum_{b<64} Zp[b][row].
__global__ __launch_bounds__(256)
void reduce4_norm(const unsigned short* __restrict__ p, const float* __restrict__ Zp,
                  unsigned short* __restrict__ yb, int n) {
  __shared__ float sZ[2];
  const int tid = threadIdx.x;
  const int row0 = blockIdx.x * 2;
  if (tid < 128) {
    const int w = tid >> 6;        // 0 or 1 -> row0 or row0+1
    const int b = tid & 63;        // partial index
    float zv = Zp[(size_t)b * 4096 + row0 + w];
#pragma unroll
    for (int off = 1; off < 64; off <<= 1) zv += __shfl_xor(zv, off);
    if (b == 0) sZ[w] = zv;
  }
  __syncthreads();
  const float inv = 1.f / sZ[tid >> 7];
  const int i = blockIdx.x * 2048 + tid * 8;
  const size_t st = (size_t)n;
  short8 a = *(const short8*)&p[i];
  short8 b = *(const short8*)&p[i + st];
  short8 c = *(const short8*)&p[i + 2 * st];
  short8 d = *(const short8*)&p[i + 3 * st];
  short8 o;
#pragma unroll
  for (int j = 0; j < 8; ++j)
    o[j] = (short)f2bf((bf2f(a[j]) + bf2f(b[j]) + bf2f(c[j]) + bf2f(d[j])) * inv);
  *(short8*)&yb[i] = o;
}

// Fused 4x weight transpose: z in {0:Wk,1:Wq(x0.06),2:Wv} -> Wt + z*1M; 3:Wo -> Wot.
__global__ __launch_bounds__(256)
void tr4_f32_bf16(const float* __restrict__ s0, const float* __restrict__ s1,
                  const float* __restrict__ s2, const float* __restrict__ s3,
                  unsigned short* __restrict__ dWt, unsigned short* __restrict__ dWot) {
  __shared__ float t[32][33];
  const int z = blockIdx.z;
  const float* src = (z == 0) ? s0 : (z == 1) ? s1 : (z == 2) ? s2 : s3;
  unsigned short* dst = (z == 3) ? dWot : dWt + (size_t)z * 1024 * 1024;
  const float scale = (z == 1) ? 0.06f : 1.0f;
  const int bx = blockIdx.x * 32;
  const int by = blockIdx.y * 32;
  const int tx = threadIdx.x, ty = threadIdx.y;
#pragma unroll
  for (int j = 0; j < 4; ++j)
    t[ty + j * 8][tx] = src[(size_t)(by + ty + j * 8) * 1024 + bx + tx];
  __syncthreads();
#pragma unroll
  for (int j = 0; j < 4; ++j)
    dst[(size_t)(bx + ty + j * 8) * 1024 + by + tx] = f2bf(t[tx][ty + j * 8] * scale);
}

// dst[c][r] = src[r][c], bf16 -> bf16. 32x32 tiles, block (32,8).
__global__ __launch_bounds__(256)
void tr_bf16(const unsigned short* __restrict__ src, int ld,
             unsigned short* __restrict__ dst, int dld) {
  __shared__ unsigned short t[32][33];
  const int bx = blockIdx.x * 32;
  const int by = blockIdx.y * 32;
  const int tx = threadIdx.x, ty = threadIdx.y;
#pragma unroll
  for (int j = 0; j < 4; ++j)
    t[ty + j * 8][tx] = src[(size_t)(by + ty + j * 8) * ld + bx + tx];
  __syncthreads();
#pragma unroll
  for (int j = 0; j < 4; ++j)
    dst[(size_t)(bx + ty + j * 8) * dld + by + tx] = t[tx][ty + j * 8];
}

__global__ __launch_bounds__(256)
void cvt_f32_bf16(const float* __restrict__ src, unsigned short* __restrict__ dst, int n) {
  const int i = (blockIdx.x * 256 + threadIdx.x) * 4;
  if (i >= n) return;
  f32x4 v = *(const f32x4*)&src[i];
  u16x4 o;
#pragma unroll
  for (int j = 0; j < 4; ++j) o[j] = f2bf(v[j]);
  *(u16x4*)&dst[i] = o;
}

extern "C" void kernel_launch(void* const* d_in, const int* in_sizes, int n_in,
                              void* d_out, int out_size, void* d_ws, size_t ws_size,
                              hipStream_t stream) {
  const float* x = (const float*)d_in[0];
  const float* Wk = (const float*)d_in[1];
  const float* Wq = (const float*)d_in[2];
  const float* Wv = (const float*)d_in[3];
  const float* Wo = (const float*)d_in[4];
  float* out = (float*)d_out;

  // workspace layout (bf16 elements); total 80 MB
  bf16* xb  = (bf16*)d_ws;                    // [4096][1024]                      [0,8) MB
  bf16* Wt  = xb + (size_t)4096 * 1024;       // [3072][1024] Wk^T|.06Wq^T|Wv^T    [8,14) MB
  bf16* KQV = Wt + (size_t)3072 * 1024;       // [4096][3072] K|Q|V                [14,38) MB
  bf16* Wot = KQV + (size_t)4096 * 3072;      // [1024][1024] Wo^T                 [38,40) MB
  bf16* Vt  = Wot + (size_t)1024 * 1024;      // [1024][4096] V^T                  [40,48) MB
  bf16* S   = Vt + (size_t)1024 * 4096;       // [4096][4096] P = exp(QK^T)        [48,80) MB
  bf16* p4  = xb;  // 4 x [4096][1024] att@V partials over dead xb/Wt/KQV[0,18)    [0,32) MB
  bf16* yb  = S;   // [4096][1024] y over dead S                                   [48,56) MB
  // Zp [64][4096] f32 = 1 MB stashed in d_out (dead until outproj writes it)
  float* Zp = out;

  const dim3 tb(32, 8);

  cvt_f32_bf16<<<dim3(4096), dim3(256), 0, stream>>>(x, (unsigned short*)xb, 4096 * 1024);
  tr4_f32_bf16<<<dim3(32, 32, 4), tb, 0, stream>>>(
      Wk, Wq, Wv, Wo, (unsigned short*)Wt, (unsigned short*)Wot);

  // KQV = xb @ Wt^T   [4096 x 3072], K=1024   (192 blocks, 6-phase 256², T1 swizzle)
  gemm256<bf16, 0><<<dim3(12, 16, 1), dim3(512), 0, stream>>>(
      xb, 1024, Wt, 1024, KQV, 3072, 1024, 0);

  // Vt = transpose of V part
  tr_bf16<<<dim3(32, 128), tb, 0, stream>>>((const unsigned short*)(KQV + 2048), 3072,
                                            (unsigned short*)Vt, 4096);

  // P = exp(Q @ K^T), Zp[64][4096] per-wave row-sum partials (256 blocks, T1 swizzle)
  gemm256x<<<dim3(16, 16, 1), dim3(512), 0, stream>>>(
      KQV + 1024, 3072, KQV, 3072, S, 4096, 1024, Zp);

  // p4[z] = P @ V, split-K=4 (64 blocks per z, 6-phase 256², T1 swizzle per z-slice)
  gemm256<bf16, 2><<<dim3(4, 16, 4), dim3(512), 0, stream>>>(
      S, 4096, Vt, 4096, p4, 1024, 1024, (size_t)4096 * 1024);

  // yb = (sum of 4 partials) / Z  (softmax normalization folded in)
  reduce4_norm<<<dim3(2048), dim3(256), 0, stream>>>(
      (const unsigned short*)p4, Zp, (unsigned short*)yb, 4096 * 1024);

  // out = yb @ Wot^T   [4096 x 1024], K=1024, fp32 out (m97 kernel, T1 swizzle)
  gemm_bt<float, 3><<<dim3(8, 32, 1), dim3(256), 0, stream>>>(
      yb, 1024, Wot, 1024, out, 1024, 1024, 0);
}